// Round 5
// baseline (938.569 us; speedup 1.0000x reference)
//
#include <hip/hip_runtime.h>

// Encoder block: LN1 -> QKV -> per-token head-mix attention -> scramble ->
// WO -> +x,LN1 -> W1+GELU (2 halves) -> W2 accum (+b2,+q2) -> LN2 in-place.
// GEMM: 256x128 block tile, 4 waves of 128x64, mfma_f32_32x32x16_bf16,
// BK=32 double-buffered LDS, one barrier/iter, staging overlapped w/ compute.
// LDS k-chunks XOR-swizzled by row bits 2-3 (bank-quad uniform frag reads).
// Workspace footprint: 152 MB (d_out doubles as the f32 residual buffer).

typedef __attribute__((ext_vector_type(8))) short s16x8;
typedef __attribute__((ext_vector_type(4))) short s16x4;
typedef __attribute__((ext_vector_type(16))) float f32x16;

__device__ __forceinline__ short f2bf(float x) {
  unsigned u = __builtin_bit_cast(unsigned, x);
  u = (u + 0x7FFFu + ((u >> 16) & 1u)) >> 16;
  return (short)u;
}
__device__ __forceinline__ float bf2f(short s) {
  unsigned u = ((unsigned)(unsigned short)s) << 16;
  return __builtin_bit_cast(float, u);
}

__device__ __forceinline__ void ld_g2l16(const short* g, short* l) {
  __builtin_amdgcn_global_load_lds(
      (const __attribute__((address_space(1))) void*)g,
      (__attribute__((address_space(3))) void*)l, 16, 0, 0);
}

// Fast GELU (tanh form via v_exp_f32; |err| ~1e-3 << bf16 noise).
__device__ __forceinline__ float fast_gelu(float v) {
  float y = 0.7978845608f * (v + 0.044715f * v * v * v);
  float ay = fabsf(y);
  float t = __expf(-2.0f * ay);
  float th = (1.0f - t) * __frcp_rn(1.0f + t);
  th = (y >= 0.f) ? th : -th;
  return 0.5f * v * (1.0f + th);
}

// ---------------------------------------------------------------------------
// GEMM: C[M,N] = A[M,K] @ BT[N,K]^T  (A, BT bf16 row-major, K-contiguous).
// EPI: 0 = store bf16; 1 = store f32; 2 = +bias, fast GELU, store bf16;
//      4 = out += acc (+bias if non-null), f32 in-place accumulate.
// Block: 256 thr = 4 waves; tile 256x128; wave tile 128x64 (4x2 of 32x32).
// LDS rows hold 32 k-shorts (4 chunks of 16 B); chunk c of row r is stored at
// slot c ^ ((r>>2)&3), so a frag read's bank quad = 4*(r&1) + (c^key) covers
// all 8 quads uniformly (8 lanes/quad = service floor).
// K-loop: double buffer, barrier -> stage(next) -> compute(cur).
// ---------------------------------------------------------------------------
template <int EPI>
__global__ __launch_bounds__(256, 2) void gemm_bt(
    const short* __restrict__ A, const short* __restrict__ BT,
    void* __restrict__ outp, const float* __restrict__ bias, int M, int N,
    int K) {
  __shared__ __align__(16) short As[2][256 * 32];  // 2 x 16 KB
  __shared__ __align__(16) short Bs[2][128 * 32];  // 2 x 8 KB

  const int lane = threadIdx.x & 63;
  const int wave = threadIdx.x >> 6;
  const int bm = blockIdx.x, bn = blockIdx.y;
  const int m31 = lane & 31;         // row/col within a 32-tile
  const int h = lane >> 5;           // k-half selector for frags
  const int wm = (wave >> 1) * 128;  // wave row base within block tile
  const int wn = (wave & 1) * 64;    // wave col base

  f32x16 acc[4][2];
#pragma unroll
  for (int i = 0; i < 4; i++)
#pragma unroll
    for (int j = 0; j < 2; j++)
#pragma unroll
      for (int r = 0; r < 16; r++) acc[i][j][r] = 0.f;

  // Staging: lane l covers (row = l>>2, chunk = (l&3) ^ ((l>>4)&3)) of its
  // 16-row segment -> LDS segment is lane-ordered contiguous (1024 B).
  const int srow = lane >> 2;
  const int sch = (lane & 3) ^ ((lane >> 4) & 3);
  const short* gA = A + (size_t)(bm * 256) * K + sch * 8;
  const short* gB = BT + (size_t)(bn * 128) * K + sch * 8;

  const int xkey = (m31 >> 2) & 3;  // frag-read XOR key (row bits 2-3)

  const int iters = K >> 5;  // BK = 32

  // Prologue: stage k=0 into buffer 0.
#pragma unroll
  for (int c = 0; c < 4; c++) {
    const int s = wave * 4 + c;
    ld_g2l16(gA + (size_t)(s * 16 + srow) * K, As[0] + s * 512);
  }
#pragma unroll
  for (int c = 0; c < 2; c++) {
    const int s = wave * 2 + c;
    ld_g2l16(gB + (size_t)(s * 16 + srow) * K, Bs[0] + s * 512);
  }

  for (int n = 0; n < iters; n++) {
    __syncthreads();  // drains vmcnt: buffer n&1 is now valid

    if (n + 1 < iters) {  // stage next iter into the other buffer
      const int kk = (n + 1) << 5;
      const int nb2 = (n + 1) & 1;
#pragma unroll
      for (int c = 0; c < 4; c++) {
        const int s = wave * 4 + c;
        ld_g2l16(gA + (size_t)(s * 16 + srow) * K + kk, As[nb2] + s * 512);
      }
#pragma unroll
      for (int c = 0; c < 2; c++) {
        const int s = wave * 2 + c;
        ld_g2l16(gB + (size_t)(s * 16 + srow) * K + kk, Bs[nb2] + s * 512);
      }
    }

    const int cb = n & 1;
#pragma unroll
    for (int ks = 0; ks < 2; ks++) {
      const int g = ks * 2 + h;       // global 16B-chunk index 0..3
      const int co = (g ^ xkey) * 8;  // swizzled chunk offset (shorts)
      s16x8 a8[4], b8[2];
#pragma unroll
      for (int i = 0; i < 4; i++)
        a8[i] = *(const s16x8*)(As[cb] + (wm + i * 32 + m31) * 32 + co);
#pragma unroll
      for (int j = 0; j < 2; j++)
        b8[j] = *(const s16x8*)(Bs[cb] + (wn + j * 32 + m31) * 32 + co);
#pragma unroll
      for (int i = 0; i < 4; i++)
#pragma unroll
        for (int j = 0; j < 2; j++)
          acc[i][j] = __builtin_amdgcn_mfma_f32_32x32x16_bf16(
              a8[i], b8[j], acc[i][j], 0, 0, 0);
    }
  }

  // Epilogue. 32x32 C/D layout: col = lane&31, row = (r&3) + 8*(r>>2) + 4*h.
  const int mb = bm * 256 + wm, nb = bn * 128 + wn;
#pragma unroll
  for (int i = 0; i < 4; i++) {
#pragma unroll
    for (int j = 0; j < 2; j++) {
#pragma unroll
      for (int r = 0; r < 16; r++) {
        const size_t row =
            (size_t)(mb + i * 32 + (r & 3) + 8 * (r >> 2) + 4 * h);
        const int col = nb + j * 32 + m31;
        float v = acc[i][j][r];
        if constexpr (EPI == 0) {
          ((short*)outp)[row * N + col] = f2bf(v);
        } else if constexpr (EPI == 1) {
          ((float*)outp)[row * N + col] = v;
        } else if constexpr (EPI == 2) {
          v += bias[col];
          ((short*)outp)[row * N + col] = f2bf(fast_gelu(v));
        } else {  // EPI == 4
          float prev = ((float*)outp)[row * N + col];
          v += prev;
          if (bias) v += bias[col];
          ((float*)outp)[row * N + col] = v;
        }
      }
    }
  }
}

// ---------------------------------------------------------------------------
// Row LayerNorm over D=1024. Optional fp32 `add` (residual). Writes fp32
// and/or bf16. One block (256 thr) per row. Safe in-place (outf == in).
// ---------------------------------------------------------------------------
__global__ __launch_bounds__(256) void ln_k(
    const float* __restrict__ in, const float* __restrict__ add,
    const float* __restrict__ g, const float* __restrict__ b,
    float* __restrict__ outf, short* __restrict__ outb) {
  const int row = blockIdx.x;
  const size_t off = (size_t)row * 1024;
  const int t = threadIdx.x;
  float4 v = ((const float4*)(in + off))[t];
  if (add) {
    float4 w = ((const float4*)(add + off))[t];
    v.x += w.x; v.y += w.y; v.z += w.z; v.w += w.w;
  }
  float s = v.x + v.y + v.z + v.w;
  float ss = v.x * v.x + v.y * v.y + v.z * v.z + v.w * v.w;
#pragma unroll
  for (int o = 32; o > 0; o >>= 1) {
    s += __shfl_xor(s, o, 64);
    ss += __shfl_xor(ss, o, 64);
  }
  __shared__ float ps[4], pss[4];
  const int lane = t & 63, wave = t >> 6;
  if (lane == 0) { ps[wave] = s; pss[wave] = ss; }
  __syncthreads();
  s = ps[0] + ps[1] + ps[2] + ps[3];
  ss = pss[0] + pss[1] + pss[2] + pss[3];
  const float mean = s * (1.0f / 1024.0f);
  const float var = ss * (1.0f / 1024.0f) - mean * mean;
  const float rstd = rsqrtf(var + 1e-6f);
  const float4 gv = ((const float4*)g)[t];
  const float4 bv = ((const float4*)b)[t];
  float4 o4;
  o4.x = (v.x - mean) * rstd * gv.x + bv.x;
  o4.y = (v.y - mean) * rstd * gv.y + bv.y;
  o4.z = (v.z - mean) * rstd * gv.z + bv.z;
  o4.w = (v.w - mean) * rstd * gv.w + bv.w;
  if (outf) ((float4*)(outf + off))[t] = o4;
  if (outb) {
    s16x4 ob;
    ob[0] = f2bf(o4.x); ob[1] = f2bf(o4.y);
    ob[2] = f2bf(o4.z); ob[3] = f2bf(o4.w);
    *(s16x4*)(outb + off + t * 4) = ob;
  }
}

// ---------------------------------------------------------------------------
// Weight convert+transpose: W[K,N] fp32 -> WT[N,K] bf16. 32x32 tiles.
// ---------------------------------------------------------------------------
__global__ __launch_bounds__(256) void wconv_t(const float* __restrict__ W,
                                               short* __restrict__ WT, int K,
                                               int N) {
  __shared__ float tile[32][33];
  const int t = threadIdx.x;
  const int c = t & 31, r = t >> 5;
  const int n0 = blockIdx.x * 32, k0 = blockIdx.y * 32;
#pragma unroll
  for (int rr = r; rr < 32; rr += 8)
    tile[rr][c] = W[(size_t)(k0 + rr) * N + n0 + c];
  __syncthreads();
#pragma unroll
  for (int rr = r; rr < 32; rr += 8)
    WT[(size_t)(n0 + rr) * K + k0 + c] = f2bf(tile[c][rr]);
}

// ---------------------------------------------------------------------------
// Per-token head-mixing attention + faithful-reshape scramble.
// ---------------------------------------------------------------------------
__global__ __launch_bounds__(256) void attn_k(const short* __restrict__ qkv,
                                              short* __restrict__ omix) {
  __shared__ float Qs[4][16][64];
  __shared__ float Ks[4][16][64];
  __shared__ float Vs[4][16][64];
  __shared__ float Ps[4][16][16];
  const int lane = threadIdx.x & 63;
  const int wave = threadIdx.x >> 6;
  const int tok = blockIdx.x * 4 + wave;
  const short* base = qkv + (size_t)tok * 3072;

#pragma unroll
  for (int half = 0; half < 2; half++) {
    const int e = half * 512 + lane * 8;
    const int h = e >> 6, d = e & 63;
    s16x8 rq = *(const s16x8*)(base + e);
    s16x8 rk = *(const s16x8*)(base + 1024 + e);
    s16x8 rv = *(const s16x8*)(base + 2048 + e);
#pragma unroll
    for (int j = 0; j < 8; j++) {
      Qs[wave][h][d + j] = bf2f(rq[j]);
      Ks[wave][h][d + j] = bf2f(rk[j]);
      Vs[wave][h][d + j] = bf2f(rv[j]);
    }
  }
  __syncthreads();

  const int h = lane & 15;
  const int g0 = (lane >> 4) * 4;
  float sc[4] = {0.f, 0.f, 0.f, 0.f};
  for (int d = 0; d < 64; d++) {
    const float qv = Qs[wave][h][d];
#pragma unroll
    for (int i = 0; i < 4; i++) sc[i] += qv * Ks[wave][g0 + i][d];
  }
#pragma unroll
  for (int i = 0; i < 4; i++) sc[i] *= 0.125f;
  float m = fmaxf(fmaxf(sc[0], sc[1]), fmaxf(sc[2], sc[3]));
  m = fmaxf(m, __shfl_xor(m, 16, 64));
  m = fmaxf(m, __shfl_xor(m, 32, 64));
  float e[4], sum = 0.f;
#pragma unroll
  for (int i = 0; i < 4; i++) { e[i] = __expf(sc[i] - m); sum += e[i]; }
  sum += __shfl_xor(sum, 16, 64);
  sum += __shfl_xor(sum, 32, 64);
  const float inv = __frcp_rn(sum);
#pragma unroll
  for (int i = 0; i < 4; i++) Ps[wave][h][g0 + i] = e[i] * inv;
  __syncthreads();

  const int d0 = (lane >> 4) * 16;
  float o[16];
#pragma unroll
  for (int dd = 0; dd < 16; dd++) o[dd] = 0.f;
  for (int gg = 0; gg < 16; gg++) {
    const float pv = Ps[wave][h][gg];
#pragma unroll
    for (int dd = 0; dd < 16; dd++) o[dd] += pv * Vs[wave][gg][d0 + dd];
  }

  const int b = tok >> 12, t = tok & 4095;
  const size_t dst =
      ((size_t)(b * 4096 + h * 256 + (t >> 4))) * 1024 + (t & 15) * 64 + d0;
  s16x8 w0, w1;
#pragma unroll
  for (int j = 0; j < 8; j++) { w0[j] = f2bf(o[j]); w1[j] = f2bf(o[8 + j]); }
  *(s16x8*)(omix + dst) = w0;
  *(s16x8*)(omix + dst + 8) = w1;
}

// ---------------------------------------------------------------------------
extern "C" void kernel_launch(void* const* d_in, const int* in_sizes, int n_in,
                              void* d_out, int out_size, void* d_ws,
                              size_t ws_size, hipStream_t stream) {
  const float* x    = (const float*)d_in[0];
  const float* wq   = (const float*)d_in[1];
  const float* wk   = (const float*)d_in[2];
  const float* wv   = (const float*)d_in[3];
  const float* wo   = (const float*)d_in[4];
  const float* ln1g = (const float*)d_in[5];
  const float* ln1b = (const float*)d_in[6];
  const float* w1   = (const float*)d_in[7];
  const float* b1   = (const float*)d_in[8];
  const float* w2   = (const float*)d_in[9];
  const float* b2   = (const float*)d_in[10];
  const float* ln2g = (const float*)d_in[11];
  const float* ln2b = (const float*)d_in[12];
  float* out = (float*)d_out;  // [16384,1024] f32; doubles as o2/q2 buffer

  char* ws = (char*)d_ws;
  const size_t MB = 1024ull * 1024ull;
  const size_t NEEDED = 152 * MB;
  if (ws_size < NEEDED) return;  // fail-numeric instead of page-fault

  short* QKV  = (short*)(ws + 0);        // phase1 [16384,3072] bf16
  short* Q2B  = (short*)(ws + 0);        // phase2 [16384,1024] bf16
  short* Hbuf = (short*)(ws + 32 * MB);  // phase2 [16384,2048] bf16
  short* X1 = (short*)(ws + 96 * MB);    // x1, then o_mixed bf16
  short* WQKVT = (short*)(ws + 128 * MB);
  short* WOT   = (short*)(ws + 134 * MB);
  short* W1T   = (short*)(ws + 136 * MB);
  short* W2aT  = (short*)(ws + 144 * MB);
  short* W2bT  = (short*)(ws + 148 * MB);

  const dim3 B256(256);

  wconv_t<<<dim3(32, 32), B256, 0, stream>>>(wq, WQKVT, 1024, 1024);
  wconv_t<<<dim3(32, 32), B256, 0, stream>>>(wk, WQKVT + 1024 * 1024, 1024, 1024);
  wconv_t<<<dim3(32, 32), B256, 0, stream>>>(wv, WQKVT + 2048 * 1024, 1024, 1024);
  wconv_t<<<dim3(32, 32), B256, 0, stream>>>(wo, WOT, 1024, 1024);
  wconv_t<<<dim3(128, 32), B256, 0, stream>>>(w1, W1T, 1024, 4096);
  wconv_t<<<dim3(32, 64), B256, 0, stream>>>(w2, W2aT, 2048, 1024);
  wconv_t<<<dim3(32, 64), B256, 0, stream>>>(w2 + 2048 * 1024, W2bT, 2048, 1024);

  // x1 = LN1(x) -> bf16
  ln_k<<<16384, B256, 0, stream>>>(x, nullptr, ln1g, ln1b, nullptr, X1);

  // QKV = x1 @ [wq|wk|wv]
  gemm_bt<0><<<dim3(64, 24), B256, 0, stream>>>(X1, WQKVT, QKV, nullptr,
                                                16384, 3072, 1024);

  // attention + scramble -> o_mixed (reuses X1 region)
  attn_k<<<4096, B256, 0, stream>>>(QKV, X1);

  // o2 = o_mixed @ wo -> f32 into d_out
  gemm_bt<1><<<dim3(64, 8), B256, 0, stream>>>(X1, WOT, out, nullptr, 16384,
                                               1024, 1024);

  // q2 = LN1(o2 + x): f32 in-place in d_out, bf16 copy in Q2B
  ln_k<<<16384, B256, 0, stream>>>(out, x, ln1g, ln1b, out, Q2B);

  // FFN half A
  gemm_bt<2><<<dim3(64, 16), B256, 0, stream>>>(Q2B, W1T, Hbuf, b1, 16384,
                                                2048, 1024);
  gemm_bt<4><<<dim3(64, 8), B256, 0, stream>>>(Hbuf, W2aT, out, nullptr,
                                               16384, 1024, 2048);

  // FFN half B
  gemm_bt<2><<<dim3(64, 16), B256, 0, stream>>>(Q2B, W1T + 2048 * 1024, Hbuf,
                                                b1 + 2048, 16384, 2048, 1024);
  gemm_bt<4><<<dim3(64, 8), B256, 0, stream>>>(Hbuf, W2bT, out, b2, 16384,
                                               1024, 2048);

  // out = LN2(y) in-place
  ln_k<<<16384, B256, 0, stream>>>(out, nullptr, ln2g, ln2b, out, nullptr);
}

// Round 6
// 918.316 us; speedup vs baseline: 1.0221x; 1.0221x over previous
//
#include <hip/hip_runtime.h>

// Encoder block: LN1 -> QKV -> per-token head-mix attention -> scramble ->
// WO -> +x,LN1 -> W1+GELU (2 halves) -> W2 accum (+b2,+q2) -> LN2 in-place.
// GEMM: 128x128 block tile, 4 waves of 64x64, mfma_f32_32x32x16_bf16,
// BK=32 double-buffered LDS, one barrier/iter, staging overlapped w/ compute.
// __launch_bounds__(256,4): <=128 regs/wave -> 4 waves/SIMD (16 waves/CU).
// LDS k-chunks XOR-swizzled by row bits 2-3 (bank-quad uniform frag reads).
// Workspace footprint: 152 MB (d_out doubles as the f32 residual buffer).

typedef __attribute__((ext_vector_type(8))) short s16x8;
typedef __attribute__((ext_vector_type(4))) short s16x4;
typedef __attribute__((ext_vector_type(16))) float f32x16;

__device__ __forceinline__ short f2bf(float x) {
  unsigned u = __builtin_bit_cast(unsigned, x);
  u = (u + 0x7FFFu + ((u >> 16) & 1u)) >> 16;
  return (short)u;
}
__device__ __forceinline__ float bf2f(short s) {
  unsigned u = ((unsigned)(unsigned short)s) << 16;
  return __builtin_bit_cast(float, u);
}

__device__ __forceinline__ void ld_g2l16(const short* g, short* l) {
  __builtin_amdgcn_global_load_lds(
      (const __attribute__((address_space(1))) void*)g,
      (__attribute__((address_space(3))) void*)l, 16, 0, 0);
}

// Fast GELU (tanh form via v_exp_f32; |err| ~1e-3 << bf16 noise).
__device__ __forceinline__ float fast_gelu(float v) {
  float y = 0.7978845608f * (v + 0.044715f * v * v * v);
  float ay = fabsf(y);
  float t = __expf(-2.0f * ay);
  float th = (1.0f - t) * __frcp_rn(1.0f + t);
  th = (y >= 0.f) ? th : -th;
  return 0.5f * v * (1.0f + th);
}

// ---------------------------------------------------------------------------
// GEMM: C[M,N] = A[M,K] @ BT[N,K]^T  (A, BT bf16 row-major, K-contiguous).
// EPI: 0 = store bf16; 1 = store f32; 2 = +bias, fast GELU, store bf16;
//      4 = out += acc (+bias if non-null), f32 in-place accumulate.
// Block: 256 thr = 4 waves (2x2); tile 128x128; wave tile 64x64 (2x2 of
// 32x32) -> 64 f32 acc/lane, total regs ~110 -> 4 waves/SIMD.
// LDS rows hold 32 k-shorts (4 chunks of 16 B); chunk c of row r stored at
// slot c ^ ((r>>2)&3): frag-read bank quad = 4*(r&1) + (c^key) covers all 8
// quads uniformly. K-loop: double buffer, barrier -> stage(next) -> compute.
// ---------------------------------------------------------------------------
template <int EPI>
__global__ __launch_bounds__(256, 4) void gemm_bt(
    const short* __restrict__ A, const short* __restrict__ BT,
    void* __restrict__ outp, const float* __restrict__ bias, int M, int N,
    int K) {
  __shared__ __align__(16) short As[2][128 * 32];  // 2 x 8 KB
  __shared__ __align__(16) short Bs[2][128 * 32];  // 2 x 8 KB

  const int lane = threadIdx.x & 63;
  const int wave = threadIdx.x >> 6;
  const int bm = blockIdx.x, bn = blockIdx.y;
  const int m31 = lane & 31;        // row/col within a 32-tile
  const int h = lane >> 5;          // k-half selector for frags
  const int wm = (wave >> 1) * 64;  // wave row base within block tile
  const int wn = (wave & 1) * 64;   // wave col base

  f32x16 acc[2][2];
#pragma unroll
  for (int i = 0; i < 2; i++)
#pragma unroll
    for (int j = 0; j < 2; j++)
#pragma unroll
      for (int r = 0; r < 16; r++) acc[i][j][r] = 0.f;

  // Staging: lane l covers (row = l>>2, chunk = (l&3) ^ ((l>>4)&3)) of its
  // 16-row segment -> LDS segment is lane-ordered contiguous (1024 B).
  const int srow = lane >> 2;
  const int sch = (lane & 3) ^ ((lane >> 4) & 3);
  const short* gA = A + (size_t)(bm * 128) * K + sch * 8;
  const short* gB = BT + (size_t)(bn * 128) * K + sch * 8;

  const int xkey = (m31 >> 2) & 3;  // frag-read XOR key (row bits 2-3)

  const int iters = K >> 5;  // BK = 32

  // Prologue: stage k=0 into buffer 0. 8 segments each for A and B;
  // wave stages 2 A-segments + 2 B-segments.
#pragma unroll
  for (int c = 0; c < 2; c++) {
    const int s = wave * 2 + c;
    ld_g2l16(gA + (size_t)(s * 16 + srow) * K, As[0] + s * 512);
    ld_g2l16(gB + (size_t)(s * 16 + srow) * K, Bs[0] + s * 512);
  }

  for (int n = 0; n < iters; n++) {
    __syncthreads();  // drains vmcnt: buffer n&1 is now valid

    if (n + 1 < iters) {  // stage next iter into the other buffer
      const int kk = (n + 1) << 5;
      const int nb2 = (n + 1) & 1;
#pragma unroll
      for (int c = 0; c < 2; c++) {
        const int s = wave * 2 + c;
        ld_g2l16(gA + (size_t)(s * 16 + srow) * K + kk, As[nb2] + s * 512);
        ld_g2l16(gB + (size_t)(s * 16 + srow) * K + kk, Bs[nb2] + s * 512);
      }
    }

    const int cb = n & 1;
#pragma unroll
    for (int ks = 0; ks < 2; ks++) {
      const int g = ks * 2 + h;       // global 16B-chunk index 0..3
      const int co = (g ^ xkey) * 8;  // swizzled chunk offset (shorts)
      s16x8 a8[2], b8[2];
#pragma unroll
      for (int i = 0; i < 2; i++)
        a8[i] = *(const s16x8*)(As[cb] + (wm + i * 32 + m31) * 32 + co);
#pragma unroll
      for (int j = 0; j < 2; j++)
        b8[j] = *(const s16x8*)(Bs[cb] + (wn + j * 32 + m31) * 32 + co);
#pragma unroll
      for (int i = 0; i < 2; i++)
#pragma unroll
        for (int j = 0; j < 2; j++)
          acc[i][j] = __builtin_amdgcn_mfma_f32_32x32x16_bf16(
              a8[i], b8[j], acc[i][j], 0, 0, 0);
    }
  }

  // Epilogue. 32x32 C/D layout: col = lane&31, row = (r&3) + 8*(r>>2) + 4*h.
  const int mb = bm * 128 + wm, nb = bn * 128 + wn;
#pragma unroll
  for (int i = 0; i < 2; i++) {
#pragma unroll
    for (int j = 0; j < 2; j++) {
#pragma unroll
      for (int r = 0; r < 16; r++) {
        const size_t row =
            (size_t)(mb + i * 32 + (r & 3) + 8 * (r >> 2) + 4 * h);
        const int col = nb + j * 32 + m31;
        float v = acc[i][j][r];
        if constexpr (EPI == 0) {
          ((short*)outp)[row * N + col] = f2bf(v);
        } else if constexpr (EPI == 1) {
          ((float*)outp)[row * N + col] = v;
        } else if constexpr (EPI == 2) {
          v += bias[col];
          ((short*)outp)[row * N + col] = f2bf(fast_gelu(v));
        } else {  // EPI == 4
          float prev = ((float*)outp)[row * N + col];
          v += prev;
          if (bias) v += bias[col];
          ((float*)outp)[row * N + col] = v;
        }
      }
    }
  }
}

// ---------------------------------------------------------------------------
// Row LayerNorm over D=1024. Optional fp32 `add` (residual). Writes fp32
// and/or bf16. One block (256 thr) per row. Safe in-place (outf == in).
// ---------------------------------------------------------------------------
__global__ __launch_bounds__(256) void ln_k(
    const float* __restrict__ in, const float* __restrict__ add,
    const float* __restrict__ g, const float* __restrict__ b,
    float* __restrict__ outf, short* __restrict__ outb) {
  const int row = blockIdx.x;
  const size_t off = (size_t)row * 1024;
  const int t = threadIdx.x;
  float4 v = ((const float4*)(in + off))[t];
  if (add) {
    float4 w = ((const float4*)(add + off))[t];
    v.x += w.x; v.y += w.y; v.z += w.z; v.w += w.w;
  }
  float s = v.x + v.y + v.z + v.w;
  float ss = v.x * v.x + v.y * v.y + v.z * v.z + v.w * v.w;
#pragma unroll
  for (int o = 32; o > 0; o >>= 1) {
    s += __shfl_xor(s, o, 64);
    ss += __shfl_xor(ss, o, 64);
  }
  __shared__ float ps[4], pss[4];
  const int lane = t & 63, wave = t >> 6;
  if (lane == 0) { ps[wave] = s; pss[wave] = ss; }
  __syncthreads();
  s = ps[0] + ps[1] + ps[2] + ps[3];
  ss = pss[0] + pss[1] + pss[2] + pss[3];
  const float mean = s * (1.0f / 1024.0f);
  const float var = ss * (1.0f / 1024.0f) - mean * mean;
  const float rstd = rsqrtf(var + 1e-6f);
  const float4 gv = ((const float4*)g)[t];
  const float4 bv = ((const float4*)b)[t];
  float4 o4;
  o4.x = (v.x - mean) * rstd * gv.x + bv.x;
  o4.y = (v.y - mean) * rstd * gv.y + bv.y;
  o4.z = (v.z - mean) * rstd * gv.z + bv.z;
  o4.w = (v.w - mean) * rstd * gv.w + bv.w;
  if (outf) ((float4*)(outf + off))[t] = o4;
  if (outb) {
    s16x4 ob;
    ob[0] = f2bf(o4.x); ob[1] = f2bf(o4.y);
    ob[2] = f2bf(o4.z); ob[3] = f2bf(o4.w);
    *(s16x4*)(outb + off + t * 4) = ob;
  }
}

// ---------------------------------------------------------------------------
// Weight convert+transpose: W[K,N] fp32 -> WT[N,K] bf16. 32x32 tiles.
// ---------------------------------------------------------------------------
__global__ __launch_bounds__(256) void wconv_t(const float* __restrict__ W,
                                               short* __restrict__ WT, int K,
                                               int N) {
  __shared__ float tile[32][33];
  const int t = threadIdx.x;
  const int c = t & 31, r = t >> 5;
  const int n0 = blockIdx.x * 32, k0 = blockIdx.y * 32;
#pragma unroll
  for (int rr = r; rr < 32; rr += 8)
    tile[rr][c] = W[(size_t)(k0 + rr) * N + n0 + c];
  __syncthreads();
#pragma unroll
  for (int rr = r; rr < 32; rr += 8)
    WT[(size_t)(n0 + rr) * K + k0 + c] = f2bf(tile[c][rr]);
}

// ---------------------------------------------------------------------------
// Per-token head-mixing attention + faithful-reshape scramble.
// ---------------------------------------------------------------------------
__global__ __launch_bounds__(256) void attn_k(const short* __restrict__ qkv,
                                              short* __restrict__ omix) {
  __shared__ float Qs[4][16][64];
  __shared__ float Ks[4][16][64];
  __shared__ float Vs[4][16][64];
  __shared__ float Ps[4][16][16];
  const int lane = threadIdx.x & 63;
  const int wave = threadIdx.x >> 6;
  const int tok = blockIdx.x * 4 + wave;
  const short* base = qkv + (size_t)tok * 3072;

#pragma unroll
  for (int half = 0; half < 2; half++) {
    const int e = half * 512 + lane * 8;
    const int h = e >> 6, d = e & 63;
    s16x8 rq = *(const s16x8*)(base + e);
    s16x8 rk = *(const s16x8*)(base + 1024 + e);
    s16x8 rv = *(const s16x8*)(base + 2048 + e);
#pragma unroll
    for (int j = 0; j < 8; j++) {
      Qs[wave][h][d + j] = bf2f(rq[j]);
      Ks[wave][h][d + j] = bf2f(rk[j]);
      Vs[wave][h][d + j] = bf2f(rv[j]);
    }
  }
  __syncthreads();

  const int h = lane & 15;
  const int g0 = (lane >> 4) * 4;
  float sc[4] = {0.f, 0.f, 0.f, 0.f};
  for (int d = 0; d < 64; d++) {
    const float qv = Qs[wave][h][d];
#pragma unroll
    for (int i = 0; i < 4; i++) sc[i] += qv * Ks[wave][g0 + i][d];
  }
#pragma unroll
  for (int i = 0; i < 4; i++) sc[i] *= 0.125f;
  float m = fmaxf(fmaxf(sc[0], sc[1]), fmaxf(sc[2], sc[3]));
  m = fmaxf(m, __shfl_xor(m, 16, 64));
  m = fmaxf(m, __shfl_xor(m, 32, 64));
  float e[4], sum = 0.f;
#pragma unroll
  for (int i = 0; i < 4; i++) { e[i] = __expf(sc[i] - m); sum += e[i]; }
  sum += __shfl_xor(sum, 16, 64);
  sum += __shfl_xor(sum, 32, 64);
  const float inv = __frcp_rn(sum);
#pragma unroll
  for (int i = 0; i < 4; i++) Ps[wave][h][g0 + i] = e[i] * inv;
  __syncthreads();

  const int d0 = (lane >> 4) * 16;
  float o[16];
#pragma unroll
  for (int dd = 0; dd < 16; dd++) o[dd] = 0.f;
  for (int gg = 0; gg < 16; gg++) {
    const float pv = Ps[wave][h][gg];
#pragma unroll
    for (int dd = 0; dd < 16; dd++) o[dd] += pv * Vs[wave][gg][d0 + dd];
  }

  const int b = tok >> 12, t = tok & 4095;
  const size_t dst =
      ((size_t)(b * 4096 + h * 256 + (t >> 4))) * 1024 + (t & 15) * 64 + d0;
  s16x8 w0, w1;
#pragma unroll
  for (int j = 0; j < 8; j++) { w0[j] = f2bf(o[j]); w1[j] = f2bf(o[8 + j]); }
  *(s16x8*)(omix + dst) = w0;
  *(s16x8*)(omix + dst + 8) = w1;
}

// ---------------------------------------------------------------------------
extern "C" void kernel_launch(void* const* d_in, const int* in_sizes, int n_in,
                              void* d_out, int out_size, void* d_ws,
                              size_t ws_size, hipStream_t stream) {
  const float* x    = (const float*)d_in[0];
  const float* wq   = (const float*)d_in[1];
  const float* wk   = (const float*)d_in[2];
  const float* wv   = (const float*)d_in[3];
  const float* wo   = (const float*)d_in[4];
  const float* ln1g = (const float*)d_in[5];
  const float* ln1b = (const float*)d_in[6];
  const float* w1   = (const float*)d_in[7];
  const float* b1   = (const float*)d_in[8];
  const float* w2   = (const float*)d_in[9];
  const float* b2   = (const float*)d_in[10];
  const float* ln2g = (const float*)d_in[11];
  const float* ln2b = (const float*)d_in[12];
  float* out = (float*)d_out;  // [16384,1024] f32; doubles as o2/q2 buffer

  char* ws = (char*)d_ws;
  const size_t MB = 1024ull * 1024ull;
  const size_t NEEDED = 152 * MB;
  if (ws_size < NEEDED) return;  // fail-numeric instead of page-fault

  short* QKV  = (short*)(ws + 0);        // phase1 [16384,3072] bf16
  short* Q2B  = (short*)(ws + 0);        // phase2 [16384,1024] bf16
  short* Hbuf = (short*)(ws + 32 * MB);  // phase2 [16384,2048] bf16
  short* X1 = (short*)(ws + 96 * MB);    // x1, then o_mixed bf16
  short* WQKVT = (short*)(ws + 128 * MB);
  short* WOT   = (short*)(ws + 134 * MB);
  short* W1T   = (short*)(ws + 136 * MB);
  short* W2aT  = (short*)(ws + 144 * MB);
  short* W2bT  = (short*)(ws + 148 * MB);

  const dim3 B256(256);

  wconv_t<<<dim3(32, 32), B256, 0, stream>>>(wq, WQKVT, 1024, 1024);
  wconv_t<<<dim3(32, 32), B256, 0, stream>>>(wk, WQKVT + 1024 * 1024, 1024, 1024);
  wconv_t<<<dim3(32, 32), B256, 0, stream>>>(wv, WQKVT + 2048 * 1024, 1024, 1024);
  wconv_t<<<dim3(32, 32), B256, 0, stream>>>(wo, WOT, 1024, 1024);
  wconv_t<<<dim3(128, 32), B256, 0, stream>>>(w1, W1T, 1024, 4096);
  wconv_t<<<dim3(32, 64), B256, 0, stream>>>(w2, W2aT, 2048, 1024);
  wconv_t<<<dim3(32, 64), B256, 0, stream>>>(w2 + 2048 * 1024, W2bT, 2048, 1024);

  // x1 = LN1(x) -> bf16
  ln_k<<<16384, B256, 0, stream>>>(x, nullptr, ln1g, ln1b, nullptr, X1);

  // QKV = x1 @ [wq|wk|wv]
  gemm_bt<0><<<dim3(128, 24), B256, 0, stream>>>(X1, WQKVT, QKV, nullptr,
                                                 16384, 3072, 1024);

  // attention + scramble -> o_mixed (reuses X1 region)
  attn_k<<<4096, B256, 0, stream>>>(QKV, X1);

  // o2 = o_mixed @ wo -> f32 into d_out
  gemm_bt<1><<<dim3(128, 8), B256, 0, stream>>>(X1, WOT, out, nullptr, 16384,
                                                1024, 1024);

  // q2 = LN1(o2 + x): f32 in-place in d_out, bf16 copy in Q2B
  ln_k<<<16384, B256, 0, stream>>>(out, x, ln1g, ln1b, out, Q2B);

  // FFN half A
  gemm_bt<2><<<dim3(128, 16), B256, 0, stream>>>(Q2B, W1T, Hbuf, b1, 16384,
                                                 2048, 1024);
  gemm_bt<4><<<dim3(128, 8), B256, 0, stream>>>(Hbuf, W2aT, out, nullptr,
                                                16384, 1024, 2048);

  // FFN half B
  gemm_bt<2><<<dim3(128, 16), B256, 0, stream>>>(Q2B, W1T + 2048 * 1024, Hbuf,
                                                 b1 + 2048, 16384, 2048, 1024);
  gemm_bt<4><<<dim3(128, 8), B256, 0, stream>>>(Hbuf, W2bT, out, b2, 16384,
                                                1024, 2048);

  // out = LN2(y) in-place
  ln_k<<<16384, B256, 0, stream>>>(out, nullptr, ln2g, ln2b, out, nullptr);
}